// Round 6
// baseline (640.517 us; speedup 1.0000x reference)
//
#include <hip/hip_runtime.h>
#include <hip/hip_bf16.h>
#include <cstddef>
#include <cstdint>

#define NB 8
#define LQ 8192
#define DMODEL 256
#define NHD 8
#define NLV 4
#define NPT 4
#define LEN_IN 19560          // 92*160 + 46*80 + 23*40 + 12*20
#define NQ (NB * LQ)          // 65536
#define MV (NB * LEN_IN)      // 156480 (= 2445 * 64, exact)

using bf16x8 = __attribute__((ext_vector_type(8))) short;
using f32x4  = __attribute__((ext_vector_type(4))) float;
using u32x4  = __attribute__((ext_vector_type(4))) unsigned int;

typedef const __attribute__((address_space(1))) void* gas_ptr;
typedef __attribute__((address_space(3))) void* las_ptr;

__device__ __forceinline__ void gl_lds16(const void* g, void* l) {
  __builtin_amdgcn_global_load_lds((gas_ptr)g, (las_ptr)l, 16, 0, 0);
}
__device__ __forceinline__ float bflo(unsigned u) {
  union { unsigned i; float f; } c; c.i = u << 16; return c.f;
}
__device__ __forceinline__ float bfhi(unsigned u) {
  union { unsigned i; float f; } c; c.i = u & 0xffff0000u; return c.f;
}
__device__ __forceinline__ bf16x8 pack8(float4 a, float4 b) {
  bf16x8 o;
  o[0] = (short)__bfloat16_as_ushort(__float2bfloat16(a.x));
  o[1] = (short)__bfloat16_as_ushort(__float2bfloat16(a.y));
  o[2] = (short)__bfloat16_as_ushort(__float2bfloat16(a.z));
  o[3] = (short)__bfloat16_as_ushort(__float2bfloat16(a.w));
  o[4] = (short)__bfloat16_as_ushort(__float2bfloat16(b.x));
  o[5] = (short)__bfloat16_as_ushort(__float2bfloat16(b.y));
  o[6] = (short)__bfloat16_as_ushort(__float2bfloat16(b.z));
  o[7] = (short)__bfloat16_as_ushort(__float2bfloat16(b.w));
  return o;
}

// ---------------------------------------------------------------------------
// W[256][N] fp32 -> Bt[N][256] bf16 (tiny; naive is fine)
// ---------------------------------------------------------------------------
__global__ __launch_bounds__(256) void transpose_bf16(
    const float* __restrict__ W, __hip_bfloat16* __restrict__ Bt, int N) {
  const int o = blockIdx.x * 256 + threadIdx.x;  // grid = N blocks
  const int n = o >> 8, k = o & 255;
  Bt[o] = __float2bfloat16(W[(size_t)k * N + n]);
}

// ---------------------------------------------------------------------------
// B-resident streaming GEMM: C[M, NT] = A[M,256] @ B[256,NT] + bias.
// Bt[NT][256] bf16 lives entirely in LDS (96/128 KB), loaded ONCE with the
// T2 XOR swizzle (applied on the pre-swizzled global source; LDS dest linear
// per m104/m173). ONE barrier per block. Main loop: grid-stride over 64-row
// chunks; A streamed global->reg with a 3-slot hand-unrolled pipeline; NO
// barriers, so loads/ds_reads/MFMAs schedule freely across steps.
// 256 thr = 4 waves; waves split columns: wave wv covers cols wv*(NT/4).
// OUT_MODE: 0 = fp32 row-major [M][256]
//           2 = bf16 value_h scatter
//           3 = fused split (colbase = blockIdx.y*NT): col<128 -> fp32
//               logits [M][128]; col>=128 -> bf16 offb [M][256] (bias2)
// A_F32: 1 = A fp32 (pack to bf16 at use), 0 = A bf16.
// ---------------------------------------------------------------------------
template <int OUT_MODE, int A_F32, int NT>
__global__ __launch_bounds__(256) void gemm_bres(
    const void* __restrict__ Av, const __hip_bfloat16* __restrict__ Bt,
    const float* __restrict__ bias, const float* __restrict__ bias2,
    void* __restrict__ Cout, void* __restrict__ Cout2, int nchunks) {
  constexpr int NJ = NT / 64;                 // col-fragments per wave
  __shared__ __hip_bfloat16 Bs[NT * 256];     // [n][k], 512 B rows, swizzled

  const int tid = threadIdx.x;
  const int wv = tid >> 6;
  const int lane = tid & 63;
  const int quad = lane >> 4;
  const int l16 = lane & 15;
  const int colbase = (OUT_MODE == 3) ? blockIdx.y * NT : 0;
  const __hip_bfloat16* BtBlk = Bt + (size_t)colbase * 256;

  // ---- B panel -> LDS, once. LDS linear; source pre-swizzled. ----
  // LDS[row*512 + c] = Bt_byte[row*512 + (c ^ ((row&7)<<4))]
  for (int c = 0; c < NT / 8; ++c) {
    const int slot = c * 4096 + tid * 16;
    const int row = slot >> 9;
    const int col = slot & 511;
    const int src = (slot & ~511) | (col ^ ((row & 7) << 4));
    gl_lds16((const char*)BtBlk + src, (char*)Bs + c * 4096 + wv * 1024);
  }
  __syncthreads();  // only barrier in the kernel

  const int cwave = wv * (NT / 4);
  const int bxor = (l16 & 7) << 4;  // row&7 == l16&7 for our read rows
  const char* BsB = (const char*)Bs;

// one K-step: af from A-slot, NJ swizzled ds_read_b128, 4*NJ MFMA
#define STEP(s, AF)                                                         \
  {                                                                         \
    bf16x8 af_[4], bf_[NJ];                                                 \
    _Pragma("unroll") for (int i = 0; i < 4; ++i) af_[i] = AF(i);           \
    _Pragma("unroll") for (int j = 0; j < NJ; ++j)                          \
      bf_[j] = *(const bf16x8*)(BsB + (cwave + j * 16 + l16) * 512 +        \
                                ((((s) << 6) + (quad << 4)) ^ bxor));       \
    _Pragma("unroll") for (int i = 0; i < 4; ++i)                           \
      _Pragma("unroll") for (int j = 0; j < NJ; ++j)                        \
        acc[i][j] = __builtin_amdgcn_mfma_f32_16x16x32_bf16(                \
            af_[i], bf_[j], acc[i][j], 0, 0, 0);                            \
  }

#pragma unroll 1
  for (int ch = blockIdx.x; ch < nchunks; ch += gridDim.x) {
    f32x4 acc[4][NJ] = {};

    if (A_F32) {
      const float* gA =
          (const float*)Av + ((size_t)ch * 64 + l16) * 256 + quad * 8;
      float4 fa0[4][2], fa1[4][2], fa2[4][2];
#define LDA32(dst, s)                                                       \
  _Pragma("unroll") for (int i = 0; i < 4; ++i) {                           \
    dst[i][0] = *(const float4*)(gA + (size_t)i * 16 * 256 + (s) * 32);     \
    dst[i][1] = *(const float4*)(gA + (size_t)i * 16 * 256 + (s) * 32 + 4); \
  }
#define AF0(i) pack8(fa0[i][0], fa0[i][1])
#define AF1(i) pack8(fa1[i][0], fa1[i][1])
#define AF2(i) pack8(fa2[i][0], fa2[i][1])
      LDA32(fa0, 0);
      LDA32(fa1, 1);
      LDA32(fa2, 2);
      STEP(0, AF0); LDA32(fa0, 3);
      STEP(1, AF1); LDA32(fa1, 4);
      STEP(2, AF2); LDA32(fa2, 5);
      STEP(3, AF0); LDA32(fa0, 6);
      STEP(4, AF1); LDA32(fa1, 7);
      STEP(5, AF2);
      STEP(6, AF0);
      STEP(7, AF1);
#undef LDA32
#undef AF0
#undef AF1
#undef AF2
    } else {
      const __hip_bfloat16* gA =
          (const __hip_bfloat16*)Av + ((size_t)ch * 64 + l16) * 256 + quad * 8;
      bf16x8 ba0[4], ba1[4], ba2[4];
#define LDA16(dst, s)                                                       \
  _Pragma("unroll") for (int i = 0; i < 4; ++i) dst[i] =                    \
      *(const bf16x8*)(gA + (size_t)i * 16 * 256 + (s) * 32);
#define AFB0(i) ba0[i]
#define AFB1(i) ba1[i]
#define AFB2(i) ba2[i]
      LDA16(ba0, 0);
      LDA16(ba1, 1);
      LDA16(ba2, 2);
      STEP(0, AFB0); LDA16(ba0, 3);
      STEP(1, AFB1); LDA16(ba1, 4);
      STEP(2, AFB2); LDA16(ba2, 5);
      STEP(3, AFB0); LDA16(ba0, 6);
      STEP(4, AFB1); LDA16(ba1, 7);
      STEP(5, AFB2);
      STEP(6, AFB0);
      STEP(7, AFB1);
#undef LDA16
#undef AFB0
#undef AFB1
#undef AFB2
    }

    // Epilogue. C/D layout: col = lane&15, row = quad*4 + reg.
#pragma unroll
    for (int j = 0; j < NJ; ++j) {
      const int col = colbase + cwave + j * 16 + l16;
      float bb;
      if (OUT_MODE == 3)
        bb = (col < 128) ? bias[col] : bias2[col - 128];
      else
        bb = bias[col];
#pragma unroll
      for (int i = 0; i < 4; ++i) {
#pragma unroll
        for (int r = 0; r < 4; ++r) {
          const int row = ch * 64 + i * 16 + quad * 4 + r;
          const float v = acc[i][j][r] + bb;
          if (OUT_MODE == 0) {
            ((float*)Cout)[(size_t)row * 256 + col] = v;
          } else if (OUT_MODE == 2) {
            const int b = row / LEN_IN;
            const int pix = row - b * LEN_IN;
            const int h = col >> 5, chn = col & 31;
            ((__hip_bfloat16*)Cout)[(((size_t)(b * 8 + h) * LEN_IN + pix) << 5) +
                                    chn] = __float2bfloat16(v);
          } else {  // OUT_MODE == 3
            if (col < 128) {
              ((float*)Cout)[(size_t)row * 128 + col] = v;
            } else {
              ((__hip_bfloat16*)Cout2)[(size_t)row * 256 + (col - 128)] =
                  __float2bfloat16(v);
            }
          }
        }
      }
    }
  }
#undef STEP
}

// ---------------------------------------------------------------------------
// Sampler v7: 2 queries per 256-thread block.
// Phase 1 unchanged (softmax + descriptor build into LDS).
// Phase 2: 16 gathers issued via asm volatile global_load_dwordx4 (saddr
// form: uniform SGPR base + 32-bit voffset) -> compiler CANNOT re-serialize;
// all 16 in flight. s_waitcnt vmcnt(0) + sched_barrier(0) fence (rule #18),
// then the FMA block.
// ---------------------------------------------------------------------------
__global__ __launch_bounds__(256, 3) void msda_sample7(
    const float* __restrict__ refp,            // (NQ, 8)
    const float* __restrict__ logits,          // (NQ, 128) fp32 raw
    const __hip_bfloat16* __restrict__ offb,   // (NQ, 256) bf16
    const __hip_bfloat16* __restrict__ vh,     // (NB*8, LEN_IN, 32)
    __hip_bfloat16* __restrict__ mid) {        // (NQ, 256) bf16
  const int q0 = blockIdx.x * 2;
  const int tid = threadIdx.x;

  __shared__ int2 s_d[2][8][17][4];

  {
    const int sq = tid >> 7;
    const int t = tid & 127;  // (h*NLV + l)*NPT + p  == h*16 + l*4 + p
    const int qg = q0 + sq;
    const int l = (t >> 2) & 3;
    constexpr int Hs[4] = {92, 46, 23, 12};
    constexpr int Ws_[4] = {160, 80, 40, 20};
    constexpr int St[4] = {0, 14720, 18400, 19320};
    const int Hl = Hs[l], Wl = Ws_[l];

    const float lg = logits[(size_t)qg * 128 + t];
    float mx = lg;
#pragma unroll
    for (int d = 1; d < 16; d <<= 1) mx = fmaxf(mx, __shfl_xor(mx, d));
    const float e = expf(lg - mx);
    float sm = e;
#pragma unroll
    for (int d = 1; d < 16; d <<= 1) sm += __shfl_xor(sm, d);
    const float w = e / sm;

    const float rx = refp[(size_t)qg * 8 + 2 * l];
    const float ry = refp[(size_t)qg * 8 + 2 * l + 1];
    const unsigned uo = *(const unsigned*)(offb + (size_t)qg * 256 + 2 * t);
    const float ox = bflo(uo), oy = bfhi(uo);

    const float x = rx * (float)Wl + ox - 0.5f;
    const float y = ry * (float)Hl + oy - 0.5f;
    const float xf = floorf(x), yf = floorf(y);
    const float wx = x - xf, wy = y - yf;
    const int x0 = (int)xf, y0 = (int)yf;
    const int x1 = x0 + 1, y1 = y0 + 1;
    const bool vx0 = (x0 >= 0) & (x0 < Wl), vx1 = (x1 >= 0) & (x1 < Wl);
    const bool vy0 = (y0 >= 0) & (y0 < Hl), vy1 = (y1 >= 0) & (y1 < Hl);
    const int cx0 = min(max(x0, 0), Wl - 1), cx1 = min(max(x1, 0), Wl - 1);
    const int cy0 = min(max(y0, 0), Hl - 1), cy1 = min(max(y1, 0), Hl - 1);

    const int o00 = (St[l] + cy0 * Wl + cx0) * 64;  // 64 B per pixel
    const int o01 = (St[l] + cy1 * Wl + cx0) * 64;
    const int dx = (cx1 - cx0) * 64;                // 0 or 64

    int2* dd = s_d[sq][t >> 4][t & 15];
    dd[0] = make_int2(o00,      __float_as_int((vx0 & vy0) ? w * (1.f - wx) * (1.f - wy) : 0.f));
    dd[1] = make_int2(o00 + dx, __float_as_int((vx1 & vy0) ? w * wx * (1.f - wy) : 0.f));
    dd[2] = make_int2(o01,      __float_as_int((vx0 & vy1) ? w * (1.f - wx) * wy : 0.f));
    dd[3] = make_int2(o01 + dx, __float_as_int((vx1 & vy1) ? w * wx * wy : 0.f));
  }
  __syncthreads();

  const int tap = tid & 3;
  const int cg = (tid >> 2) & 3;   // 4 channel-groups x 8 ch = 32 ch
  const int h = (tid >> 4) & 7;
  const int sq = tid >> 7;
  const int qg = q0 + sq;
  const int bq = q0 >> 13;         // batch; same for both sub-queries

  const char* vbase = (const char*)vh + (size_t)bq * (8ULL * LEN_IN * 64);
  const int voff0 = h * (LEN_IN * 64) + cg * 16;
  const int2* sd = &s_d[sq][h][0][tap];

  // issue ALL 16 gathers via asm (results pinned live, 16 in flight)
  float w[16];
  u32x4 u[16];
#pragma unroll
  for (int j = 0; j < 16; ++j) {
    const int2 dw = sd[j * 4];  // ds_read_b64, imm offset j*32
    w[j] = __int_as_float(dw.y);
    const unsigned voff = (unsigned)(voff0 + dw.x);
    asm volatile("global_load_dwordx4 %0, %1, %2"
                 : "=v"(u[j])
                 : "v"(voff), "s"(vbase));
  }
  asm volatile("s_waitcnt vmcnt(0)" ::: "memory");
  __builtin_amdgcn_sched_barrier(0);

  float a[8] = {};
#pragma unroll
  for (int j = 0; j < 16; ++j) {
    a[0] += w[j] * bflo(u[j][0]); a[1] += w[j] * bfhi(u[j][0]);
    a[2] += w[j] * bflo(u[j][1]); a[3] += w[j] * bfhi(u[j][1]);
    a[4] += w[j] * bflo(u[j][2]); a[5] += w[j] * bfhi(u[j][2]);
    a[6] += w[j] * bflo(u[j][3]); a[7] += w[j] * bfhi(u[j][3]);
  }

  // reduce over the 4 tap lanes (quad-local -> DPP adds)
#pragma unroll
  for (int i = 0; i < 8; ++i) a[i] += __shfl_xor(a[i], 1);
#pragma unroll
  for (int i = 0; i < 8; ++i) a[i] += __shfl_xor(a[i], 2);

  if (tap == 0) {
    unsigned short* mp =
        (unsigned short*)mid + (size_t)qg * 256 + h * 32 + cg * 8;
    int4 o;
    o.x = (int)((unsigned)__bfloat16_as_ushort(__float2bfloat16(a[0])) |
                ((unsigned)__bfloat16_as_ushort(__float2bfloat16(a[1])) << 16));
    o.y = (int)((unsigned)__bfloat16_as_ushort(__float2bfloat16(a[2])) |
                ((unsigned)__bfloat16_as_ushort(__float2bfloat16(a[3])) << 16));
    o.z = (int)((unsigned)__bfloat16_as_ushort(__float2bfloat16(a[4])) |
                ((unsigned)__bfloat16_as_ushort(__float2bfloat16(a[5])) << 16));
    o.w = (int)((unsigned)__bfloat16_as_ushort(__float2bfloat16(a[6])) |
                ((unsigned)__bfloat16_as_ushort(__float2bfloat16(a[7])) << 16));
    *(int4*)mp = o;
  }
}

// ---------------------------------------------------------------------------
// Launch
// ---------------------------------------------------------------------------
extern "C" void kernel_launch(void* const* d_in, const int* in_sizes, int n_in,
                              void* d_out, int out_size, void* d_ws,
                              size_t ws_size, hipStream_t stream) {
  const float* query = (const float*)d_in[0];
  const float* refp = (const float*)d_in[1];
  const float* inflat = (const float*)d_in[2];
  const float* W_off = (const float*)d_in[5];
  const float* b_off = (const float*)d_in[6];
  const float* W_attn = (const float*)d_in[7];
  const float* b_attn = (const float*)d_in[8];
  const float* W_val = (const float*)d_in[9];
  const float* b_val = (const float*)d_in[10];
  const float* W_out = (const float*)d_in[11];
  const float* b_out = (const float*)d_in[12];
  float* out = (float*)d_out;

  // Workspace layout (bytes):
  char* ws = (char*)d_ws;
  __hip_bfloat16* vh = (__hip_bfloat16*)(ws);                    // [64][19560][32]
  float* logits = (float*)(ws + 80117760ULL);                    // [65536][128] f32
  __hip_bfloat16* offb = (__hip_bfloat16*)(ws + 113672192ULL);   // [65536][256]
  __hip_bfloat16* mid = (__hip_bfloat16*)(ws + 147226624ULL);    // [65536][256]
  __hip_bfloat16* Btv = (__hip_bfloat16*)(ws + 180781056ULL);    // [256][256]
  __hip_bfloat16* Btc = (__hip_bfloat16*)(ws + 180912128ULL);    // [384][256] attn||off
  __hip_bfloat16* Btw = (__hip_bfloat16*)(ws + 181108736ULL);    // [256][256]
  // total 181,239,808 B

  // weight transposes (tiny)
  transpose_bf16<<<256, 256, 0, stream>>>(W_val, Btv, 256);
  transpose_bf16<<<128, 256, 0, stream>>>(W_attn, Btc, 128);
  transpose_bf16<<<256, 256, 0, stream>>>(W_off, Btc + 128 * 256, 256);
  transpose_bf16<<<256, 256, 0, stream>>>(W_out, Btw, 256);

  // 1. value = inflat @ W_val + b_val -> head-major bf16 value_h  (A fp32)
  gemm_bres<2, 1, 256><<<256, 256, 0, stream>>>(
      inflat, Btv, b_val, nullptr, vh, nullptr, MV / 64);
  // 2+3 fused: [logits | offsets] = query @ [W_attn | W_off]  (A fp32)
  gemm_bres<3, 1, 192><<<dim3(128, 2), 256, 0, stream>>>(
      query, Btc, b_attn, b_off, logits, offb, NQ / 64);
  // 4. sampling (softmax fused, 2 queries/block) -> mid bf16
  msda_sample7<<<NQ / 2, 256, 0, stream>>>(refp, logits, offb, vh, mid);
  // 5. out = mid @ W_out + b_out -> fp32 d_out  (A bf16)
  gemm_bres<0, 0, 256><<<256, 256, 0, stream>>>(
      mid, Btw, b_out, nullptr, out, nullptr, NQ / 64);
}

// Round 7
// 549.385 us; speedup vs baseline: 1.1659x; 1.1659x over previous
//
#include <hip/hip_runtime.h>
#include <hip/hip_bf16.h>
#include <cstddef>
#include <cstdint>

#define NB 8
#define LQ 8192
#define DMODEL 256
#define NHD 8
#define NLV 4
#define NPT 4
#define LEN_IN 19560          // 92*160 + 46*80 + 23*40 + 12*20
#define NQ (NB * LQ)          // 65536
#define MV (NB * LEN_IN)      // 156480
#define MVP 156544            // MV padded to multiple of 128 (1223*128)

using bf16x8 = __attribute__((ext_vector_type(8))) short;
using f32x4  = __attribute__((ext_vector_type(4))) float;

typedef const __attribute__((address_space(1))) void* gas_ptr;
typedef __attribute__((address_space(3))) void* las_ptr;

__device__ __forceinline__ void gl_lds16(const void* g, void* l) {
  __builtin_amdgcn_global_load_lds((gas_ptr)g, (las_ptr)l, 16, 0, 0);
}
__device__ __forceinline__ float bflo(unsigned u) {
  union { unsigned i; float f; } c; c.i = u << 16; return c.f;
}
__device__ __forceinline__ float bfhi(unsigned u) {
  union { unsigned i; float f; } c; c.i = u & 0xffff0000u; return c.f;
}
__device__ __forceinline__ bf16x8 pack8(float4 a, float4 b) {
  bf16x8 o;
  o[0] = (short)__bfloat16_as_ushort(__float2bfloat16(a.x));
  o[1] = (short)__bfloat16_as_ushort(__float2bfloat16(a.y));
  o[2] = (short)__bfloat16_as_ushort(__float2bfloat16(a.z));
  o[3] = (short)__bfloat16_as_ushort(__float2bfloat16(a.w));
  o[4] = (short)__bfloat16_as_ushort(__float2bfloat16(b.x));
  o[5] = (short)__bfloat16_as_ushort(__float2bfloat16(b.y));
  o[6] = (short)__bfloat16_as_ushort(__float2bfloat16(b.z));
  o[7] = (short)__bfloat16_as_ushort(__float2bfloat16(b.w));
  return o;
}

// ---------------------------------------------------------------------------
// W[256][N] fp32 -> Bt[N][256] bf16 (tiny; naive is fine)
// ---------------------------------------------------------------------------
__global__ __launch_bounds__(256) void transpose_bf16(
    const float* __restrict__ W, __hip_bfloat16* __restrict__ Bt, int N) {
  const int o = blockIdx.x * 256 + threadIdx.x;  // grid = N blocks
  const int n = o >> 8, k = o & 255;
  Bt[o] = __float2bfloat16(W[(size_t)k * N + n]);
}

// ---------------------------------------------------------------------------
// Counted-vmcnt MFMA GEMM: C[M, NT] = A[M,256] @ B[256,NT] + bias.
// Full-N per block; 512 thr = 8 waves (2 row x 4 col); tile 128 x NT, BK=32,
// 8 K-tiles. Double-buffered A/B LDS, tiles staged 2 AHEAD; raw s_barrier
// (no vmcnt drain) + asm s_waitcnt vmcnt(ISS) where ISS = per-iter VMEM
// issues (T3/T4 counted pattern, m218). Fragment-read 8-way bank conflict
// fixed by slot-XOR swizzle: LDS dest linear, SOURCE pre-swizzled
// (m104/m173); reads use slot quad^((l16>>1)&3) -> 2 lanes/bank (free).
// A_F32=1: A fp32 -> regs -> pack8 -> ds_write (slot-linear dest, swizzled
// src chunk). A_F32=0: A bf16 via lds-dma like B.
// OUT_MODE: 0 = fp32 [M][256]; 2 = bf16 value_h scatter;
//           3 = fused: col<128 -> fp32 logits [M][128], col>=128 -> bf16
//               offb [M][256] (bias2).
// ---------------------------------------------------------------------------
template <int OUT_MODE, int A_F32, int NT>
__global__ __launch_bounds__(512) void gemm_cnt(
    const void* __restrict__ Av, const __hip_bfloat16* __restrict__ Bt,
    const float* __restrict__ bias, const float* __restrict__ bias2,
    void* __restrict__ Cout, void* __restrict__ Cout2, int M_valid) {
  constexpr int NJ = NT / 64;    // col fragments per wave
  constexpr int NCB = NT / 128;  // B dma calls per tile (8 KB each)
  __shared__ __hip_bfloat16 Asb[2][128 * 32];
  __shared__ __hip_bfloat16 Bsb[2][NT * 32];

  const int tid = threadIdx.x;
  const int wv = tid >> 6;
  const int lane = tid & 63;
  const int quad = lane >> 4;
  const int l16 = lane & 15;
  const int bm = blockIdx.x * 128;
  const int rw = (wv & 1) * 64;            // wave row offset
  const int cwave = (wv >> 1) * (NT / 4);  // wave col offset
  const int swz = (tid & 3) ^ ((tid >> 3) & 3);       // staging src slot xor
  const int rsw = (quad ^ ((l16 >> 1) & 3)) << 4;     // read slot byte off

  // B staging source (linear LDS dest; row = c*128 + (tid>>2)):
  const char* gB = (const char*)Bt + (size_t)(tid >> 2) * 512 + swz * 16;

  // A staging
  const char* gA16 = nullptr;
  const float* gA32 = nullptr;
  bool okA = true;
  if (A_F32) {
    const int r = tid >> 2;
    okA = (bm + r) < M_valid;
    gA32 = (const float*)Av + (size_t)(bm + r) * 256 + swz * 8;
  } else {
    gA16 = (const char*)Av + (size_t)(bm + (tid >> 2)) * 512 + swz * 16;
  }
  // A ds_write dest: LINEAR slot (tid&3); the src chunk is the swizzled one.
  char* const dA0 = (char*)&Asb[0][0] + (tid >> 2) * 64 + (tid & 3) * 16;

#define STAGE_B(t, p)                                                   \
  { _Pragma("unroll") for (int c = 0; c < NCB; ++c)                     \
      gl_lds16(gB + (size_t)c * 65536 + (t) * 64,                       \
               (char*)&Bsb[p][0] + c * 8192 + wv * 1024); }
#define STAGE_A16(t, p)                                                 \
  gl_lds16(gA16 + (t) * 64, (char*)&Asb[p][0] + wv * 1024)
#define LOAD_A32(t, fa)                                                 \
  {                                                                     \
    if (okA) {                                                          \
      fa[0] = *(const float4*)(gA32 + (t) * 32);                        \
      fa[1] = *(const float4*)(gA32 + (t) * 32 + 4);                    \
    } else {                                                            \
      fa[0] = fa[1] = make_float4(0.f, 0.f, 0.f, 0.f);                  \
    }                                                                   \
  }
#define PACK_A(p, fa) *(bf16x8*)(dA0 + (p) * 8192) = pack8(fa[0], fa[1])
#define WAIT_ISS()                                                      \
  {                                                                     \
    if constexpr (A_F32 && NT == 256)                                   \
      asm volatile("s_waitcnt vmcnt(4)" ::: "memory");                  \
    else if constexpr (A_F32 && NT == 384)                              \
      asm volatile("s_waitcnt vmcnt(5)" ::: "memory");                  \
    else                                                                \
      asm volatile("s_waitcnt vmcnt(3)" ::: "memory");                  \
    asm volatile("s_waitcnt lgkmcnt(0)" ::: "memory");                  \
  }
#define BAR()                                                           \
  {                                                                     \
    __builtin_amdgcn_sched_barrier(0);                                  \
    __builtin_amdgcn_s_barrier();                                       \
    __builtin_amdgcn_sched_barrier(0);                                  \
  }
#define COMPUTE(p)                                                      \
  {                                                                     \
    bf16x8 af[4], bf[NJ];                                               \
    _Pragma("unroll") for (int i = 0; i < 4; ++i)                       \
        af[i] = *(const bf16x8*)((const char*)&Asb[p][0] +              \
                                 (rw + i * 16 + l16) * 64 + rsw);       \
    _Pragma("unroll") for (int j = 0; j < NJ; ++j)                      \
        bf[j] = *(const bf16x8*)((const char*)&Bsb[p][0] +              \
                                 (cwave + j * 16 + l16) * 64 + rsw);    \
    _Pragma("unroll") for (int i = 0; i < 4; ++i)                       \
        _Pragma("unroll") for (int j = 0; j < NJ; ++j) acc[i][j] =      \
        __builtin_amdgcn_mfma_f32_16x16x32_bf16(af[i], bf[j],           \
                                                acc[i][j], 0, 0, 0);    \
  }

  f32x4 acc[4][NJ] = {};
  float4 faA[2], faB[2];

  // prologue: stage tiles 0 and 1 (2-deep)
  if (A_F32) LOAD_A32(0, faA);
  STAGE_B(0, 0);
  if (!A_F32) STAGE_A16(0, 0);
  if (A_F32) LOAD_A32(1, faB);
  STAGE_B(1, 1);
  if (!A_F32) STAGE_A16(1, 1);
  if (A_F32) PACK_A(0, faA);  // auto vmcnt wait on faA

  // main: t = 0..5 (full unroll; parity static)
#pragma unroll
  for (int t = 0; t < 6; ++t) {
    WAIT_ISS();           // tile t resident (ISS newer in flight)
    BAR();                // all waves' chunks visible
    COMPUTE(t & 1);
    BAR();                // all waves done reading buf[t&1]
    if (A_F32) {
      if ((t + 1) & 1) { PACK_A(1, faB); } else { PACK_A(0, faA); }
      if (t & 1) { LOAD_A32(t + 2, faB); } else { LOAD_A32(t + 2, faA); }
    } else {
      STAGE_A16(t + 2, t & 1);
    }
    STAGE_B(t + 2, t & 1);
  }
  // t = 6: no further stages; pack A(7)
  WAIT_ISS();
  BAR();
  COMPUTE(0);
  BAR();
  if (A_F32) PACK_A(1, faB);
  // t = 7: final tile
  asm volatile("s_waitcnt vmcnt(0)" ::: "memory");
  asm volatile("s_waitcnt lgkmcnt(0)" ::: "memory");
  BAR();
  COMPUTE(1);

#undef STAGE_B
#undef STAGE_A16
#undef LOAD_A32
#undef PACK_A
#undef WAIT_ISS
#undef BAR
#undef COMPUTE

  // Epilogue. C/D layout: col = lane&15, row = quad*4 + reg.
#pragma unroll
  for (int j = 0; j < NJ; ++j) {
    const int col = cwave + j * 16 + l16;
    float bb;
    if (OUT_MODE == 3)
      bb = (col < 128) ? bias[col] : bias2[col - 128];
    else
      bb = bias[col];
#pragma unroll
    for (int i = 0; i < 4; ++i) {
#pragma unroll
      for (int r = 0; r < 4; ++r) {
        const int row = bm + rw + i * 16 + quad * 4 + r;
        const float v = acc[i][j][r] + bb;
        if (OUT_MODE == 0) {
          ((float*)Cout)[(size_t)row * NT + col] = v;
        } else if (OUT_MODE == 2) {
          if (row < M_valid) {
            const int b = row / LEN_IN;
            const int pix = row - b * LEN_IN;
            const int h = col >> 5, chn = col & 31;
            ((__hip_bfloat16*)Cout)[(((size_t)(b * 8 + h) * LEN_IN + pix) << 5) +
                                    chn] = __float2bfloat16(v);
          }
        } else {  // OUT_MODE == 3
          if (col < 128) {
            ((float*)Cout)[(size_t)row * 128 + col] = v;
          } else {
            ((__hip_bfloat16*)Cout2)[(size_t)row * 256 + (col - 128)] =
                __float2bfloat16(v);
          }
        }
      }
    }
  }
}

// ---------------------------------------------------------------------------
// Sampler v6 (R5 version, measured 151 us): 2 queries per 256-thread block.
// Phase 1: softmax + descriptor build into LDS. Phase 2: 16 descriptors,
// 16 uint4 gathers, FMA block; launch_bounds(256,4).
// ---------------------------------------------------------------------------
__global__ __launch_bounds__(256, 4) void msda_sample6(
    const float* __restrict__ refp,            // (NQ, 8)
    const float* __restrict__ logits,          // (NQ, 128) fp32 raw
    const __hip_bfloat16* __restrict__ offb,   // (NQ, 256) bf16
    const __hip_bfloat16* __restrict__ vh,     // (NB*8, LEN_IN, 32)
    __hip_bfloat16* __restrict__ mid) {        // (NQ, 256) bf16
  const int q0 = blockIdx.x * 2;
  const int tid = threadIdx.x;

  __shared__ int2 s_d[2][8][17][4];

  {
    const int sq = tid >> 7;
    const int t = tid & 127;  // (h*NLV + l)*NPT + p  == h*16 + l*4 + p
    const int qg = q0 + sq;
    const int l = (t >> 2) & 3;
    constexpr int Hs[4] = {92, 46, 23, 12};
    constexpr int Ws_[4] = {160, 80, 40, 20};
    constexpr int St[4] = {0, 14720, 18400, 19320};
    const int Hl = Hs[l], Wl = Ws_[l];

    const float lg = logits[(size_t)qg * 128 + t];
    float mx = lg;
#pragma unroll
    for (int d = 1; d < 16; d <<= 1) mx = fmaxf(mx, __shfl_xor(mx, d));
    const float e = expf(lg - mx);
    float sm = e;
#pragma unroll
    for (int d = 1; d < 16; d <<= 1) sm += __shfl_xor(sm, d);
    const float w = e / sm;

    const float rx = refp[(size_t)qg * 8 + 2 * l];
    const float ry = refp[(size_t)qg * 8 + 2 * l + 1];
    const unsigned uo = *(const unsigned*)(offb + (size_t)qg * 256 + 2 * t);
    const float ox = bflo(uo), oy = bfhi(uo);

    const float x = rx * (float)Wl + ox - 0.5f;
    const float y = ry * (float)Hl + oy - 0.5f;
    const float xf = floorf(x), yf = floorf(y);
    const float wx = x - xf, wy = y - yf;
    const int x0 = (int)xf, y0 = (int)yf;
    const int x1 = x0 + 1, y1 = y0 + 1;
    const bool vx0 = (x0 >= 0) & (x0 < Wl), vx1 = (x1 >= 0) & (x1 < Wl);
    const bool vy0 = (y0 >= 0) & (y0 < Hl), vy1 = (y1 >= 0) & (y1 < Hl);
    const int cx0 = min(max(x0, 0), Wl - 1), cx1 = min(max(x1, 0), Wl - 1);
    const int cy0 = min(max(y0, 0), Hl - 1), cy1 = min(max(y1, 0), Hl - 1);

    const int o00 = (St[l] + cy0 * Wl + cx0) * 64;  // 64 B per pixel
    const int o01 = (St[l] + cy1 * Wl + cx0) * 64;
    const int dx = (cx1 - cx0) * 64;                // 0 or 64

    int2* dd = s_d[sq][t >> 4][t & 15];
    dd[0] = make_int2(o00,      __float_as_int((vx0 & vy0) ? w * (1.f - wx) * (1.f - wy) : 0.f));
    dd[1] = make_int2(o00 + dx, __float_as_int((vx1 & vy0) ? w * wx * (1.f - wy) : 0.f));
    dd[2] = make_int2(o01,      __float_as_int((vx0 & vy1) ? w * (1.f - wx) * wy : 0.f));
    dd[3] = make_int2(o01 + dx, __float_as_int((vx1 & vy1) ? w * wx * wy : 0.f));
  }
  __syncthreads();

  const int tap = tid & 3;
  const int cg = (tid >> 2) & 3;   // 4 channel-groups x 8 ch = 32 ch
  const int h = (tid >> 4) & 7;
  const int sq = tid >> 7;
  const int qg = q0 + sq;
  const int bq = q0 >> 13;         // batch; same for both sub-queries

  const char* vbase = (const char*)vh + (size_t)bq * (8ULL * LEN_IN * 64);
  const int voff0 = h * (LEN_IN * 64) + cg * 16;
  const int2* sd = &s_d[sq][h][0][tap];

  // issue ALL 16 gathers before any use
  float w[16];
  uint4 u[16];
#pragma unroll
  for (int j = 0; j < 16; ++j) {
    const int2 dw = sd[j * 4];  // ds_read_b64, imm offset j*32
    w[j] = __int_as_float(dw.y);
    u[j] = *(const uint4*)(vbase + (unsigned)(voff0 + dw.x));
  }

  float a[8] = {};
#pragma unroll
  for (int j = 0; j < 16; ++j) {
    a[0] += w[j] * bflo(u[j].x); a[1] += w[j] * bfhi(u[j].x);
    a[2] += w[j] * bflo(u[j].y); a[3] += w[j] * bfhi(u[j].y);
    a[4] += w[j] * bflo(u[j].z); a[5] += w[j] * bfhi(u[j].z);
    a[6] += w[j] * bflo(u[j].w); a[7] += w[j] * bfhi(u[j].w);
  }

  // reduce over the 4 tap lanes (quad-local -> DPP adds)
#pragma unroll
  for (int i = 0; i < 8; ++i) a[i] += __shfl_xor(a[i], 1);
#pragma unroll
  for (int i = 0; i < 8; ++i) a[i] += __shfl_xor(a[i], 2);

  if (tap == 0) {
    unsigned short* mp =
        (unsigned short*)mid + (size_t)qg * 256 + h * 32 + cg * 8;
    int4 o;
    o.x = (int)((unsigned)__bfloat16_as_ushort(__float2bfloat16(a[0])) |
                ((unsigned)__bfloat16_as_ushort(__float2bfloat16(a[1])) << 16));
    o.y = (int)((unsigned)__bfloat16_as_ushort(__float2bfloat16(a[2])) |
                ((unsigned)__bfloat16_as_ushort(__float2bfloat16(a[3])) << 16));
    o.z = (int)((unsigned)__bfloat16_as_ushort(__float2bfloat16(a[4])) |
                ((unsigned)__bfloat16_as_ushort(__float2bfloat16(a[5])) << 16));
    o.w = (int)((unsigned)__bfloat16_as_ushort(__float2bfloat16(a[6])) |
                ((unsigned)__bfloat16_as_ushort(__float2bfloat16(a[7])) << 16));
    *(int4*)mp = o;
  }
}

// ---------------------------------------------------------------------------
// Launch
// ---------------------------------------------------------------------------
extern "C" void kernel_launch(void* const* d_in, const int* in_sizes, int n_in,
                              void* d_out, int out_size, void* d_ws,
                              size_t ws_size, hipStream_t stream) {
  const float* query = (const float*)d_in[0];
  const float* refp = (const float*)d_in[1];
  const float* inflat = (const float*)d_in[2];
  const float* W_off = (const float*)d_in[5];
  const float* b_off = (const float*)d_in[6];
  const float* W_attn = (const float*)d_in[7];
  const float* b_attn = (const float*)d_in[8];
  const float* W_val = (const float*)d_in[9];
  const float* b_val = (const float*)d_in[10];
  const float* W_out = (const float*)d_in[11];
  const float* b_out = (const float*)d_in[12];
  float* out = (float*)d_out;

  // Workspace layout (bytes):
  char* ws = (char*)d_ws;
  __hip_bfloat16* vh = (__hip_bfloat16*)(ws);                    // [64][19560][32]
  float* logits = (float*)(ws + 80117760ULL);                    // [65536][128] f32
  __hip_bfloat16* offb = (__hip_bfloat16*)(ws + 113672192ULL);   // [65536][256]
  __hip_bfloat16* mid = (__hip_bfloat16*)(ws + 147226624ULL);    // [65536][256]
  __hip_bfloat16* Btv = (__hip_bfloat16*)(ws + 180781056ULL);    // [256][256]
  __hip_bfloat16* Btc = (__hip_bfloat16*)(ws + 180912128ULL);    // [384][256] attn||off
  __hip_bfloat16* Btw = (__hip_bfloat16*)(ws + 181108736ULL);    // [256][256]
  // total 181,239,808 B

  // weight transposes (tiny)
  transpose_bf16<<<256, 256, 0, stream>>>(W_val, Btv, 256);
  transpose_bf16<<<128, 256, 0, stream>>>(W_attn, Btc, 128);
  transpose_bf16<<<256, 256, 0, stream>>>(W_off, Btc + 128 * 256, 256);
  transpose_bf16<<<256, 256, 0, stream>>>(W_out, Btw, 256);

  // 1. value = inflat @ W_val + b_val -> head-major bf16 value_h  (A fp32)
  gemm_cnt<2, 1, 256><<<MVP / 128, 512, 0, stream>>>(
      inflat, Btv, b_val, nullptr, vh, nullptr, MV);
  // 2+3 fused: [logits | offsets] = query @ [W_attn | W_off]  (A fp32)
  gemm_cnt<3, 1, 384><<<NQ / 128, 512, 0, stream>>>(
      query, Btc, b_attn, b_off, logits, offb, NQ);
  // 4. sampling (softmax fused, 2 queries/block) -> mid bf16
  msda_sample6<<<NQ / 2, 256, 0, stream>>>(refp, logits, offb, vh, mid);
  // 5. out = mid @ W_out + b_out -> fp32 d_out  (A bf16, lds-dma)
  gemm_cnt<0, 0, 256><<<NQ / 128, 512, 0, stream>>>(
      mid, Btw, b_out, nullptr, out, nullptr, NQ);
}